// Round 1
// baseline (341.767 us; speedup 1.0000x reference)
//
#include <hip/hip_runtime.h>
#include <hip/hip_bf16.h>
#include <stdint.h>

typedef __bf16 bf16x8 __attribute__((ext_vector_type(8)));
typedef float  f32x4  __attribute__((ext_vector_type(4)));

#define VOCAB 4096
#define DIM   256
#define NROWS 65536          // 32*2048
#define ROWS_PER_BLOCK 128
#define ROWS_PER_WAVE  32    // 2 rowsets of 16
#define CTILE 64             // codebook cols staged per LDS tile
#define LDS_STRIDE 264       // 256 + 8 bf16 pad -> 2-way (free) bank pattern

static __device__ __forceinline__ uint16_t f2bf(float f) {
    __bf16 h = (__bf16)f;
    union { __bf16 h; uint16_t u; } c; c.h = h; return c.u;
}

// Prep: ebf = bf16(-2*emb), e2[v] = sum(emb[v]^2) fp32, zero the loss slot.
__global__ void vq_prep(const float* __restrict__ emb, uint16_t* __restrict__ ebf,
                        float* __restrict__ e2, float* __restrict__ loss_slot) {
    int wave = threadIdx.x >> 6, lane = threadIdx.x & 63;
    int row = blockIdx.x * 4 + wave;                      // 1024 blocks * 4 rows
    const float4* src = (const float4*)(emb + (size_t)row * DIM);
    float4 v = src[lane];
    float ss = v.x*v.x + v.y*v.y + v.z*v.z + v.w*v.w;
    ushort4 o;
    o.x = f2bf(-2.f*v.x); o.y = f2bf(-2.f*v.y);
    o.z = f2bf(-2.f*v.z); o.w = f2bf(-2.f*v.w);
    ((ushort4*)(ebf + (size_t)row * DIM))[lane] = o;
    #pragma unroll
    for (int off = 32; off; off >>= 1) ss += __shfl_down(ss, off);
    if (lane == 0) e2[row] = ss;
    if (blockIdx.x == 0 && threadIdx.x == 0) loss_slot[0] = 0.f;
}

__global__ __launch_bounds__(256) void vq_main(
        const float* __restrict__ x, const uint16_t* __restrict__ ebf,
        const float* __restrict__ e2, const float* __restrict__ emb,
        float* __restrict__ out, float* __restrict__ loss_slot) {
    __shared__ __align__(16) uint16_t Blds[CTILE * LDS_STRIDE];
    __shared__ int idx_lds[ROWS_PER_BLOCK];
    __shared__ float wsum[4];

    const int tid  = threadIdx.x;
    const int wave = tid >> 6;
    const int lane = tid & 63;
    const int quad = lane >> 4;
    const int l16  = lane & 15;
    const int rowblock = blockIdx.x * ROWS_PER_BLOCK;
    const int waverow  = rowblock + wave * ROWS_PER_WAVE;

    // ---- Load this wave's 32 x-rows as A fragments (held in regs all loop) ----
    // A layout: A[m = lane&15][k = quad*8 + j], j=0..7 contiguous.
    bf16x8 Afrag[2][8];
    #pragma unroll
    for (int rs = 0; rs < 2; ++rs) {
        const float* xrow = x + (size_t)(waverow + rs*16 + l16) * DIM;
        #pragma unroll
        for (int ch = 0; ch < 8; ++ch) {
            const float4* p = (const float4*)(xrow + ch*32 + quad*8);
            float4 a = p[0], b = p[1];
            bf16x8 f;
            f[0]=(__bf16)a.x; f[1]=(__bf16)a.y; f[2]=(__bf16)a.z; f[3]=(__bf16)a.w;
            f[4]=(__bf16)b.x; f[5]=(__bf16)b.y; f[6]=(__bf16)b.z; f[7]=(__bf16)b.w;
            Afrag[rs][ch] = f;
        }
    }

    float minv[2][4];
    int   mini[2][4];
    #pragma unroll
    for (int rs = 0; rs < 2; ++rs)
        #pragma unroll
        for (int r = 0; r < 4; ++r) { minv[rs][r] = 3.402823466e+38f; mini[rs][r] = 0; }

    // ---- Main loop over codebook in tiles of CTILE cols ----
    for (int ct = 0; ct < VOCAB / CTILE; ++ct) {
        const int colbase = ct * CTILE;
        // Stage CTILE x 256 bf16 into padded LDS: 2048 16B segments, 8 rounds.
        #pragma unroll
        for (int r = 0; r < 8; ++r) {
            int seg = r * 256 + tid;
            int col = seg >> 5;            // 32 segments per col
            int ko  = (seg & 31) << 3;     // element offset, 8 elems = 16B
            uint4 v = *(const uint4*)(ebf + (size_t)(colbase + col) * DIM + ko);
            *(uint4*)&Blds[col * LDS_STRIDE + ko] = v;
        }
        __syncthreads();

        #pragma unroll
        for (int sub = 0; sub < 4; ++sub) {
            const int colv = colbase + sub*16 + l16;
            float ez = e2[colv];
            f32x4 acc0 = {ez, ez, ez, ez};   // C init folds +e2[col]
            f32x4 acc1 = {ez, ez, ez, ez};
            #pragma unroll
            for (int ch = 0; ch < 8; ++ch) {
                bf16x8 b = *(const bf16x8*)&Blds[(sub*16 + l16) * LDS_STRIDE + ch*32 + quad*8];
                acc0 = __builtin_amdgcn_mfma_f32_16x16x32_bf16(Afrag[0][ch], b, acc0, 0, 0, 0);
                acc1 = __builtin_amdgcn_mfma_f32_16x16x32_bf16(Afrag[1][ch], b, acc1, 0, 0, 0);
            }
            // C layout: row = quad*4 + r, col = l16. Strict < keeps smallest col on ties.
            #pragma unroll
            for (int r = 0; r < 4; ++r) {
                if (acc0[r] < minv[0][r]) { minv[0][r] = acc0[r]; mini[0][r] = colv; }
                if (acc1[r] < minv[1][r]) { minv[1][r] = acc1[r]; mini[1][r] = colv; }
            }
        }
        __syncthreads();
    }

    // ---- Reduce across the 16 lanes of each quad (same 4 rows, different cols) ----
    #pragma unroll
    for (int rs = 0; rs < 2; ++rs) {
        #pragma unroll
        for (int r = 0; r < 4; ++r) {
            float v = minv[rs][r]; int ix = mini[rs][r];
            #pragma unroll
            for (int off = 8; off; off >>= 1) {
                float ov = __shfl_xor(v, off);
                int   oi = __shfl_xor(ix, off);
                if (ov < v || (ov == v && oi < ix)) { v = ov; ix = oi; }
            }
            if (l16 == 0) idx_lds[wave * ROWS_PER_WAVE + rs*16 + quad*4 + r] = ix;
        }
    }
    __syncthreads();

    // ---- Epilogue: gather emb[idx] (fp32 exact), write out, accumulate loss ----
    float lsum = 0.f;
    #pragma unroll 4
    for (int it = 0; it < 32; ++it) {
        int fi  = it * 256 + tid;          // float4 index within block tile
        int row = fi >> 6;                 // 64 float4 per row
        int c4  = fi & 63;
        int e   = idx_lds[row];
        float4 q  = ((const float4*)(emb + (size_t)e * DIM))[c4];
        float4 xv = ((const float4*)(x + (size_t)(rowblock + row) * DIM))[c4];
        ((float4*)(out + (size_t)(rowblock + row) * DIM))[c4] = q;
        float dx = q.x - xv.x, dy = q.y - xv.y, dz = q.z - xv.z, dw = q.w - xv.w;
        lsum += dx*dx + dy*dy + dz*dz + dw*dw;
    }
    #pragma unroll
    for (int off = 32; off; off >>= 1) lsum += __shfl_down(lsum, off);
    if (lane == 0) wsum[wave] = lsum;
    __syncthreads();
    if (tid == 0) {
        float s = wsum[0] + wsum[1] + wsum[2] + wsum[3];
        atomicAdd(loss_slot, s * (1.25f / 16777216.f));
    }
}

extern "C" void kernel_launch(void* const* d_in, const int* in_sizes, int n_in,
                              void* d_out, int out_size, void* d_ws, size_t ws_size,
                              hipStream_t stream) {
    const float* x   = (const float*)d_in[0];   // [32,2048,256]
    const float* emb = (const float*)d_in[1];   // [4096,256]
    float* out = (float*)d_out;                 // 16777216 quantised_st + 1 loss
    uint16_t* ebf = (uint16_t*)d_ws;                          // 2 MB bf16(-2*emb)
    float* e2 = (float*)((char*)d_ws + (size_t)VOCAB*DIM*2);  // 16 KB
    float* loss_slot = out + (size_t)NROWS * DIM;

    vq_prep<<<VOCAB/4, 256, 0, stream>>>(emb, ebf, e2, loss_slot);
    vq_main<<<NROWS/ROWS_PER_BLOCK, 256, 0, stream>>>(x, ebf, e2, emb, out, loss_slot);
}